// Round 13
// baseline (177.804 us; speedup 1.0000x reference)
//
#include <hip/hip_runtime.h>
#include <hip/hip_fp16.h>

#define BB    32
#define CIN   256
#define COUT  256
#define HH    28
#define WW    28
#define NPIX  784
#define HP    30
#define WP    30

#define BM    128
#define BN    128
#define NT    7               // ceil(784/128)

// workspace:
//   wgen: fragment-ordered filters for 32x32x16 MFMA. Per (b,mtH) slice
//         294912 f16 (= 128 m-rows x 2304 K). Chunk (8 f16):
//           (c32*9 + khw)*512 + s*256 + sub32*64 + 32*khalf + (m&31)
//         holds A[m][ch = c32*32 + s*16 + khalf*8 + e] at tap khw,
//         sub32 = (m&127)>>5. Lane-linear: khalf=lane>>5, m&31=lane&31.
//   xpad: [b][30][30][256] f16 zero-padded NHWC
#define SLICE_ELEMS 294912                       // 128 * 2304
#define WGEN_ELEMS  ((size_t)BB * 2 * SLICE_ELEMS)
#define XPAD_OFF    (WGEN_ELEMS)

#define PREP_GENW  512        // (og 0..31) x (c32 0..7) x (bh 0..1)
#define PREP_GENX  960
#define PREP_GRID  (PREP_GENW + PREP_GENX)

typedef _Float16 f16x8  __attribute__((ext_vector_type(8)));
typedef float    f32x16 __attribute__((ext_vector_type(16)));

static __device__ __forceinline__ ushort f2h_bits(float v) {
    __half h = __float2half(v);
    return *reinterpret_cast<ushort*>(&h);
}

static __device__ __forceinline__ void gll16(const ushort* g, ushort* l) {
    __builtin_amdgcn_global_load_lds(
        (const __attribute__((address_space(1))) unsigned int*)g,
        (__attribute__((address_space(3))) unsigned int*)l, 16, 0, 0);
}

#define KOFF(k) (((k) / 3) * 30 + ((k) % 3))

// ---------------------------------------------------------------------------
// Fused prep kernel.
//   [0, 512)     : gen_w V4 -> wgen (32x32-fragment order). Block
//                  (og, c32, bh): 16 samples, w_lds double-buffered,
//                  ONE barrier per sample, 128-B-run stores.
//   [512, 1472)  : gen_x -> xpad f16 zero-padded NHWC
// ---------------------------------------------------------------------------
__global__ __launch_bounds__(256) void prep(const float* __restrict__ weight,
                                            const float* __restrict__ se,
                                            const float* __restrict__ x,
                                            ushort* __restrict__ wgen,
                                            ushort* __restrict__ xpad) {
    __shared__ __align__(16) char smem[29696];
    const int bid = blockIdx.x;
    const int tid = threadIdx.x;

    if (bid < PREP_GENW) {
        // ---- gen_w V4 ----
        const int og  = bid >> 4;            // 0..31 (8 consecutive o)
        const int bh  = (bid >> 3) & 1;      // sample half
        const int c32 = bid & 7;             // channel chunk
        const int ol  = tid >> 5;            // o_local 0..7
        const int cl  = tid & 31;            // c_local 0..31
        const int o   = og * 8 + ol;
        const int c   = c32 * 32 + cl;
        const int mtH = og >> 4;

        float*  se_sh = (float*)smem;                  // 1024 B
        ushort* w_lds = (ushort*)(smem + 1024);        // 2 x [9*8][40] = 11520 B

        se_sh[tid] = se[tid];

        float4 wr[18];
        const float4* wp = (const float4*)(weight + ((size_t)o * CIN + c) * 72);
#pragma unroll
        for (int i = 0; i < 18; ++i) wr[i] = wp[i];

        // store decomposition: chunk j (0..287): khw=j>>5, r=j&31:
        //   ol_j=r&7, half_j=(r>>3)&1, s_j=r>>4
        const int r0    = tid & 31;
        const int khw0  = tid >> 5;
        const int ol0   = r0 & 7;
        const int half0 = (r0 >> 3) & 1;
        const int s0_   = r0 >> 4;
        const int sub32 = (og & 15) >> 2;
        const int lanep = (og & 3) * 8;
        const int dst0  = ((c32 * 9 + khw0) * 512 + s0_ * 256 + sub32 * 64
                           + 32 * half0 + lanep + ol0) * 8;
        const int src0  = (khw0 * 8 + ol0) * 40 + s0_ * 16 + half0 * 8;
        // j1 = 256+tid (tid<32): khw=8, r=tid
        const int ol1   = tid & 7;
        const int half1 = (tid >> 3) & 1;
        const int s1_   = tid >> 4;          // 0..1 for tid<32
        const int dst1  = ((c32 * 9 + 8) * 512 + s1_ * 256 + sub32 * 64
                           + 32 * half1 + lanep + ol1) * 8;
        const int src1  = (8 * 8 + ol1) * 40 + s1_ * 16 + half1 * 8;

        __syncthreads();

        for (int bi = 0; bi < 16; ++bi) {
            const int b   = bh * 16 + bi;
            const int buf = (bi & 1) * 2880;           // ushort offset
            const float s0 = se_sh[b * 8 + 0], s1 = se_sh[b * 8 + 1];
            const float s2 = se_sh[b * 8 + 2], s3 = se_sh[b * 8 + 3];
            const float s4 = se_sh[b * 8 + 4], s5 = se_sh[b * 8 + 5];
            const float s6 = se_sh[b * 8 + 6], s7 = se_sh[b * 8 + 7];
#pragma unroll
            for (int k = 0; k < 9; ++k) {
                const float4 w0 = wr[2 * k + 0];
                const float4 w1 = wr[2 * k + 1];
                const float v = w0.x * s0 + w0.y * s1 + w0.z * s2 + w0.w * s3
                              + w1.x * s4 + w1.y * s5 + w1.z * s6 + w1.w * s7;
                w_lds[buf + (k * 8 + ol) * 40 + cl] = f2h_bits(v);
            }
            __syncthreads();
            ushort* slice_base = wgen + (size_t)(b * 2 + mtH) * SLICE_ELEMS;
            *(uint4*)(slice_base + dst0) = *(const uint4*)(w_lds + buf + src0);
            if (tid < 32)
                *(uint4*)(slice_base + dst1) = *(const uint4*)(w_lds + buf + src1);
        }
    } else {
        // ---- gen_x ----
        const int idx = bid - PREP_GENW;
        const int hp  = idx % HP;
        const int b   = idx / HP;
        ushort* row = xpad + ((size_t)b * HP + hp) * WP * CIN;

        if (hp == 0 || hp == HP - 1) {
            uint* r32 = (uint*)row;
            for (int i = tid; i < (WP * CIN) / 2; i += 256) r32[i] = 0u;
            return;
        }
        {
            uint* c0 = (uint*)row;
            uint* c1 = (uint*)(row + (WP - 1) * CIN);
            if (tid < 128)       c0[tid] = 0u;
            else                 c1[tid - 128] = 0u;
        }
        float* lds = (float*)smem;                     // 29696 B
        const int h = hp - 1;
        const float* xr = x + (size_t)b * CIN * NPIX + h * WW;

        for (int f = tid; f < CIN * WW; f += 256) {
            const int cc = f / WW;
            const int w  = f % WW;
            lds[cc * (WW + 1) + w] = xr[(size_t)cc * NPIX + w];
        }
        __syncthreads();
        for (int g2 = tid; g2 < WW * CIN; g2 += 256) {
            const int w  = g2 >> 8;
            const int cc = g2 & 255;
            row[(w + 1) * CIN + cc] = f2h_bits(lds[cc * (WW + 1) + w]);
        }
    }
}

// ---------------------------------------------------------------------------
// dconv: implicit-GEMM on mfma_f32_32x32x16_f16 (half the instruction count
// of the 16x16x32 version). Block 128x128, wave 64x64 as 2x2 of 32-frags.
// Per k16-step: 4 MFMA (~32 CU-cyc) vs 2 ds_read_b128 (24 cyc) -> MFMA-dense.
// A direct global->VGPR (lane-linear fragment order, 3-slot ring distance 2);
// B from shifted-window LDS patch (identical staging to r11, dbuf, 1 barrier
// per c32). Grid 448, XCD-grouped (7 nt per slice on one XCD).
// ---------------------------------------------------------------------------
__global__ __launch_bounds__(256, 2) void dconv_mfma(const ushort* __restrict__ wgen,
                                                     const ushort* __restrict__ xpad,
                                                     const float* __restrict__ bias,
                                                     float* __restrict__ out) {
    const int bid    = blockIdx.x;
    const int g      = bid & 7;
    const int s      = bid >> 3;           // 0..55
    const int nt     = s % NT;
    const int slice2 = g + 8 * (s / NT);   // 0..63 = b*2 + mtH
    const int b      = slice2 >> 1;
    const int mtH    = slice2 & 1;

    const int tid  = threadIdx.x;
    const int lane = tid & 63;
    const int wave = tid >> 6;
    const int wm   = wave >> 1;            // m 64-half
    const int wn   = wave & 1;             // n 64-half
    const int n5   = lane & 31;
    const int half = lane >> 5;

    __shared__ ushort Psh[2][7680];        // 2 x 15360 B: [q(4)][row(8)][w(30)][8]

    const int mo   = mtH * 128 + wm * 64;
    const int no   = nt * BN + wn * 64;
    const int h_lo = (nt * BN) / WW;

    // A: lane-linear fragment order; frag mi at + mi*64, k16-step st at + st*256
    const f16x8* ag = (const f16x8*)(wgen + (size_t)slice2 * SLICE_ELEMS)
                      + wm * 128 + lane;
    const ushort* xp = xpad + (size_t)b * HP * WP * CIN;

    // patch staging offsets (identical to r11: 960 chunks of 16 B)
    int p_goff[4], p_loff[4];
    bool p_ok[4];
#pragma unroll
    for (int r = 0; r < 4; ++r) {
        const int j = r * 256 + tid;
        p_ok[r] = (j < 960);
        const int jj  = p_ok[r] ? j : 0;
        const int qc  = jj / 240;
        const int rem = jj % 240;
        const int rr  = rem / 30;
        const int ww  = rem % 30;
        int srow = h_lo + rr;
        if (srow > 29) srow = 29;
        p_goff[r] = (srow * WP + ww) * CIN + qc * 8;
        p_loff[r] = jj * 8;
    }

    int pixbase[2], pst[2];
#pragma unroll
    for (int nj = 0; nj < 2; ++nj) {
        const int p  = no + nj * 32 + n5;
        pst[nj] = p;
        const int pc = p > (NPIX - 1) ? (NPIX - 1) : p;
        pixbase[nj] = (pc / WW - h_lo) * 30 + (pc % WW);
    }

    f32x16 acc[2][2];
#pragma unroll
    for (int mi = 0; mi < 2; ++mi)
#pragma unroll
        for (int nj = 0; nj < 2; ++nj)
            acc[mi][nj] = (f32x16)(0.f);

    // ---- prologue: patch c32=0; A-ring fill (st 0,1 -> slots 0,1) ----
#pragma unroll
    for (int r = 0; r < 4; ++r)
        if (p_ok[r]) gll16(xp + p_goff[r], &Psh[0][p_loff[r]]);

    f16x8 afr[3][2];
#pragma unroll
    for (int sl = 0; sl < 2; ++sl) {
        const f16x8* ap = ag + sl * 256;
#pragma unroll
        for (int mi = 0; mi < 2; ++mi) afr[sl][mi] = ap[mi * 64];
    }

    f16x8 bfr[2][2];

    for (int c32 = 0; c32 < 8; ++c32) {
        __syncthreads();   // patch(c32) resident; prev buffer free

        if (c32 < 7) {
            const int nb = (c32 + 1) & 1;
#pragma unroll
            for (int r = 0; r < 4; ++r)
                if (p_ok[r]) gll16(xp + p_goff[r] + (c32 + 1) * 32,
                                   &Psh[nb][p_loff[r]]);
        }

        const f16x8* Pc = (const f16x8*)Psh[c32 & 1];

        // bf slot 0 = (khw 0, s 0): planes q = half
#pragma unroll
        for (int nj = 0; nj < 2; ++nj)
            bfr[0][nj] = Pc[half * 240 + pixbase[nj]];

#pragma unroll
        for (int st18 = 0; st18 < 18; ++st18) {
            const int st = c32 * 18 + st18;
            // A prefetch, distance 2 (slot arithmetic compile-time: 18%3==0)
            int sp = st + 2; if (sp > 143) sp = 143;
            const f16x8* apf = ag + sp * 256;
#pragma unroll
            for (int mi = 0; mi < 2; ++mi)
                afr[(st18 + 2) % 3][mi] = apf[mi * 64];
            // bf prefetch, distance 1 (within c32)
            if (st18 < 17) {
                const int ns = (st18 + 1) & 1;
                const int nk = (st18 + 1) >> 1;
#pragma unroll
                for (int nj = 0; nj < 2; ++nj)
                    bfr[ns][nj] = Pc[(ns * 2 + half) * 240 + pixbase[nj] + KOFF(nk)];
            }
            // consume
#pragma unroll
            for (int mi = 0; mi < 2; ++mi)
#pragma unroll
                for (int nj = 0; nj < 2; ++nj)
                    acc[mi][nj] = __builtin_amdgcn_mfma_f32_32x32x16_f16(
                        afr[st18 % 3][mi], bfr[st18 & 1][nj], acc[mi][nj], 0, 0, 0);
        }
    }

    // ---- epilogue: row = (reg&3) + 8*(reg>>2) + 4*half, col = lane&31 ----
    float* ob = out + (size_t)b * COUT * NPIX;
#pragma unroll
    for (int mi = 0; mi < 2; ++mi) {
#pragma unroll
        for (int rg = 0; rg < 4; ++rg) {
            const int m0 = mo + mi * 32 + 8 * rg + 4 * half;
            const float4 bv = *(const float4*)(bias + m0);
#pragma unroll
            for (int nj = 0; nj < 2; ++nj) {
                const int p = pst[nj];
                if (p < NPIX) {
                    ob[(size_t)(m0 + 0) * NPIX + p] = acc[mi][nj][rg * 4 + 0] + bv.x;
                    ob[(size_t)(m0 + 1) * NPIX + p] = acc[mi][nj][rg * 4 + 1] + bv.y;
                    ob[(size_t)(m0 + 2) * NPIX + p] = acc[mi][nj][rg * 4 + 2] + bv.z;
                    ob[(size_t)(m0 + 3) * NPIX + p] = acc[mi][nj][rg * 4 + 3] + bv.w;
                }
            }
        }
    }
}

extern "C" void kernel_launch(void* const* d_in, const int* in_sizes, int n_in,
                              void* d_out, int out_size, void* d_ws, size_t ws_size,
                              hipStream_t stream) {
    const float* x      = (const float*)d_in[0];
    const float* se     = (const float*)d_in[1];
    const float* weight = (const float*)d_in[2];
    const float* bias   = (const float*)d_in[3];
    float* out          = (float*)d_out;

    ushort* wgen = (ushort*)d_ws;
    ushort* xpad = (ushort*)d_ws + XPAD_OFF;
    (void)ws_size; (void)in_sizes; (void)n_in; (void)out_size;

    prep<<<dim3(PREP_GRID), dim3(256), 0, stream>>>(weight, se, x, wgen, xpad);
    dconv_mfma<<<dim3(BB * 2 * NT), dim3(256), 0, stream>>>(wgen, xpad, bias, out);
}

// Round 14
// 146.486 us; speedup vs baseline: 1.2138x; 1.2138x over previous
//
#include <hip/hip_runtime.h>
#include <hip/hip_fp16.h>

#define BB    32
#define CIN   256
#define COUT  256
#define HH    28
#define WW    28
#define NPIX  784
#define HP    30
#define WP    30

#define BM    64
#define BN    128
#define NT    7               // 784 / 128 (ceil)

// workspace:
//   wgen2: fragment-ordered filters (16x16x32 MFMA), per (b,mtH) slice
//          294912 f16. Chunk (8 f16): (c32*9+khw)*512 + sub*64 + quad*16 + col
//          holds A[m = mtH*128 + sub*16 + col][ch = c32*32 + quad*8 .. +7]
//   xpad : [b][30][30][256] f16 zero-padded NHWC
#define SLICE_ELEMS 294912                       // 128 * 2304
#define WGEN_ELEMS  ((size_t)BB * 2 * SLICE_ELEMS)
#define XPAD_OFF    (WGEN_ELEMS)

#define PREP_GENW  512        // (og 0..31) x (c32 0..7) x (bh 0..1)
#define PREP_GENX  960
#define PREP_GRID  (PREP_GENW + PREP_GENX)

typedef _Float16 f16x8 __attribute__((ext_vector_type(8)));
typedef float    f32x4 __attribute__((ext_vector_type(4)));

static __device__ __forceinline__ ushort f2h_bits(float v) {
    __half h = __float2half(v);
    return *reinterpret_cast<ushort*>(&h);
}

static __device__ __forceinline__ void gll16(const ushort* g, ushort* l) {
    __builtin_amdgcn_global_load_lds(
        (const __attribute__((address_space(1))) unsigned int*)g,
        (__attribute__((address_space(3))) unsigned int*)l, 16, 0, 0);
}

#define KOFF(k) (((k) / 3) * 30 + ((k) % 3))

// ---------------------------------------------------------------------------
// Fused prep kernel.
//   [0, 512)     : gen_w V5 -> wgen2 (r11 fragment layout). Block (og,c32,bh):
//                  16 samples, LDS double-buffered -> ONE barrier per sample,
//                  weight read once, stores in 128-B runs.
//   [512, 1472)  : gen_x -> xpad f16 zero-padded NHWC (unchanged)
// ---------------------------------------------------------------------------
__global__ __launch_bounds__(256) void prep(const float* __restrict__ weight,
                                            const float* __restrict__ se,
                                            const float* __restrict__ x,
                                            ushort* __restrict__ wgen2,
                                            ushort* __restrict__ xpad) {
    __shared__ __align__(16) char smem[29696];
    const int bid = blockIdx.x;
    const int tid = threadIdx.x;

    if (bid < PREP_GENW) {
        // ---- gen_w V5 ----
        const int og  = bid >> 4;            // 0..31 (8 consecutive o)
        const int bh  = (bid >> 3) & 1;      // sample half
        const int c32 = bid & 7;             // channel chunk
        const int ol  = tid >> 5;            // o_local 0..7
        const int cl  = tid & 31;            // c_local 0..31
        const int o   = og * 8 + ol;
        const int c   = c32 * 32 + cl;
        const int mtH = og >> 4;

        float*  se_sh = (float*)smem;                  // 1024 B
        ushort* w_lds = (ushort*)(smem + 1024);        // 2 x 2880 ushort = 11520 B

        se_sh[tid] = se[tid];

        float4 wr[18];
        const float4* wp = (const float4*)(weight + ((size_t)o * CIN + c) * 72);
#pragma unroll
        for (int i = 0; i < 18; ++i) wr[i] = wp[i];

        // store decomposition: 288 chunks = 9 khw x (4 quad x 8 ol)
        // j0 = tid: khw0 = tid>>5, r0 = tid&31 -> q0 = r0>>3, ol0 = r0&7
        const int khw0 = tid >> 5;
        const int r0   = tid & 31;
        const int q0   = r0 >> 3;
        const int ol0  = r0 & 7;
        const int o0   = og * 8 + ol0;
        const int sub0 = (o0 >> 4) & 7, col0 = o0 & 15;
        const int dst0 = ((c32 * 9 + khw0) * 512 + sub0 * 64 + q0 * 16 + col0) * 8;
        const int src0 = (khw0 * 8 + ol0) * 40 + q0 * 8;
        // j1 = 256+tid (tid<32): khw=8, r=tid
        const int q1   = tid >> 3;           // 0..3
        const int ol1  = tid & 7;
        const int o1   = og * 8 + ol1;
        const int sub1 = (o1 >> 4) & 7, col1 = o1 & 15;
        const int dst1 = ((c32 * 9 + 8) * 512 + sub1 * 64 + q1 * 16 + col1) * 8;
        const int src1 = (8 * 8 + ol1) * 40 + q1 * 8;

        __syncthreads();

        for (int bi = 0; bi < 16; ++bi) {
            const int b   = bh * 16 + bi;
            const int buf = (bi & 1) * 2880;           // ushort offset
            const float s0 = se_sh[b * 8 + 0], s1 = se_sh[b * 8 + 1];
            const float s2 = se_sh[b * 8 + 2], s3 = se_sh[b * 8 + 3];
            const float s4 = se_sh[b * 8 + 4], s5 = se_sh[b * 8 + 5];
            const float s6 = se_sh[b * 8 + 6], s7 = se_sh[b * 8 + 7];
#pragma unroll
            for (int k = 0; k < 9; ++k) {
                const float4 w0 = wr[2 * k + 0];
                const float4 w1 = wr[2 * k + 1];
                const float v = w0.x * s0 + w0.y * s1 + w0.z * s2 + w0.w * s3
                              + w1.x * s4 + w1.y * s5 + w1.z * s6 + w1.w * s7;
                w_lds[buf + (k * 8 + ol) * 40 + cl] = f2h_bits(v);
            }
            __syncthreads();   // taps(buf) complete; prev stores also done
            ushort* slice_base = wgen2 + (size_t)(b * 2 + mtH) * SLICE_ELEMS;
            *(uint4*)(slice_base + dst0) = *(const uint4*)(w_lds + buf + src0);
            if (tid < 32)
                *(uint4*)(slice_base + dst1) = *(const uint4*)(w_lds + buf + src1);
        }
    } else {
        // ---- gen_x ----
        const int idx = bid - PREP_GENW;
        const int hp  = idx % HP;
        const int b   = idx / HP;
        ushort* row = xpad + ((size_t)b * HP + hp) * WP * CIN;

        if (hp == 0 || hp == HP - 1) {
            uint* r32 = (uint*)row;
            for (int i = tid; i < (WP * CIN) / 2; i += 256) r32[i] = 0u;
            return;
        }
        {
            uint* c0 = (uint*)row;
            uint* c1 = (uint*)(row + (WP - 1) * CIN);
            if (tid < 128)       c0[tid] = 0u;
            else                 c1[tid - 128] = 0u;
        }
        float* lds = (float*)smem;
        const int h = hp - 1;
        const float* xr = x + (size_t)b * CIN * NPIX + h * WW;

        for (int f = tid; f < CIN * WW; f += 256) {
            const int cc = f / WW;
            const int w  = f % WW;
            lds[cc * (WW + 1) + w] = xr[(size_t)cc * NPIX + w];
        }
        __syncthreads();
        for (int g2 = tid; g2 < WW * CIN; g2 += 256) {
            const int w  = g2 >> 8;
            const int cc = g2 & 255;
            row[(w + 1) * CIN + cc] = f2h_bits(lds[cc * (WW + 1) + w]);
        }
    }
}

// ---------------------------------------------------------------------------
// dconv (r11, byte-identical): BM=64 implicit-GEMM, 896 blocks = 3.5/CU.
// Wave tile 32x64: 8 MFMA, 2 A-loads, 4 bf reads per step. Psh dbuf
// (1 barrier/c32); A-ring 3 slots distance 2; XCD-grouped.
// ---------------------------------------------------------------------------
__global__ __launch_bounds__(256, 4) void dconv_mfma(const ushort* __restrict__ wgen2,
                                                     const ushort* __restrict__ xpad,
                                                     const float* __restrict__ bias,
                                                     float* __restrict__ out) {
    const int bid    = blockIdx.x;
    const int g      = bid & 7;
    const int s      = bid >> 3;           // 0..111
    const int t      = s % 14;
    const int nt     = t % 7;
    const int mtl    = t / 7;
    const int slice2 = g + 8 * (s / 14);   // 0..63 = b*2 + mtH
    const int b      = slice2 >> 1;
    const int mtH    = slice2 & 1;

    const int tid  = threadIdx.x;
    const int lane = tid & 63;
    const int wave = tid >> 6;
    const int wm   = wave >> 1;
    const int wn   = wave & 1;
    const int col  = lane & 15;
    const int quad = lane >> 4;

    __shared__ ushort Psh[2][7680];        // 2 x 15360 B

    const int mo   = mtH * 128 + mtl * 64 + wm * 32;
    const int no   = nt * BN + wn * 64;
    const int h_lo = (nt * BN) / WW;

    const f16x8* ag = (const f16x8*)(wgen2 + (size_t)slice2 * SLICE_ELEMS)
                      + (mtl * 4 + wm * 2) * 64 + lane;
    const ushort* xp = xpad + (size_t)b * HP * WP * CIN;

    int p_goff[4], p_loff[4];
    bool p_ok[4];
#pragma unroll
    for (int r = 0; r < 4; ++r) {
        const int j = r * 256 + tid;
        p_ok[r] = (j < 960);
        const int jj  = p_ok[r] ? j : 0;
        const int qc  = jj / 240;
        const int rem = jj % 240;
        const int rr  = rem / 30;
        const int ww  = rem % 30;
        int srow = h_lo + rr;
        if (srow > 29) srow = 29;
        p_goff[r] = (srow * WP + ww) * CIN + qc * 8;
        p_loff[r] = jj * 8;
    }

    int pixbase[4], pst[4];
#pragma unroll
    for (int j = 0; j < 4; ++j) {
        const int p  = no + j * 16 + col;
        pst[j] = p;
        const int pc = p > (NPIX - 1) ? (NPIX - 1) : p;
        pixbase[j] = (pc / WW - h_lo) * 30 + (pc % WW);
    }

    f32x4 acc[2][4];
#pragma unroll
    for (int mi = 0; mi < 2; ++mi)
#pragma unroll
        for (int nj = 0; nj < 4; ++nj)
            acc[mi][nj] = (f32x4){0.f, 0.f, 0.f, 0.f};

    // ---- prologue ----
#pragma unroll
    for (int r = 0; r < 4; ++r)
        if (p_ok[r]) gll16(xp + p_goff[r], &Psh[0][p_loff[r]]);

    f16x8 afr[3][2];
#pragma unroll
    for (int mi = 0; mi < 2; ++mi) afr[0][mi] = ag[mi * 64];
    {
        const f16x8* a1 = ag + (1 << 9);
#pragma unroll
        for (int mi = 0; mi < 2; ++mi) afr[1][mi] = a1[mi * 64];
    }

    f16x8 bfr[2][4];

    for (int c32 = 0; c32 < 8; ++c32) {
        __syncthreads();

        if (c32 < 7) {
            const int nb = (c32 + 1) & 1;
#pragma unroll
            for (int r = 0; r < 4; ++r)
                if (p_ok[r]) gll16(xp + p_goff[r] + (c32 + 1) * 32,
                                   &Psh[nb][p_loff[r]]);
        }

        const f16x8* Pc = (const f16x8*)Psh[c32 & 1];

#pragma unroll
        for (int j = 0; j < 4; ++j)
            bfr[0][j] = Pc[quad * 240 + pixbase[j] + KOFF(0)];

#pragma unroll
        for (int khw = 0; khw < 9; ++khw) {
            const int st = c32 * 9 + khw;
            int sp = st + 2; if (sp > 71) sp = 71;
            const f16x8* apf = ag + ((size_t)sp << 9);
#pragma unroll
            for (int mi = 0; mi < 2; ++mi)
                afr[(khw + 2) % 3][mi] = apf[mi * 64];
            if (khw < 8) {
#pragma unroll
                for (int j = 0; j < 4; ++j)
                    bfr[(khw + 1) & 1][j] = Pc[quad * 240 + pixbase[j] + KOFF(khw + 1)];
            }
#pragma unroll
            for (int mi = 0; mi < 2; ++mi)
#pragma unroll
                for (int nj = 0; nj < 4; ++nj)
                    acc[mi][nj] = __builtin_amdgcn_mfma_f32_16x16x32_f16(
                        afr[khw % 3][mi], bfr[khw & 1][nj], acc[mi][nj], 0, 0, 0);
        }
    }

    // ---- epilogue ----
    float* ob = out + (size_t)b * COUT * NPIX;
#pragma unroll
    for (int mi = 0; mi < 2; ++mi) {
        const int m = mo + mi * 16 + quad * 4;
        const float4 bv = *(const float4*)(bias + m);
#pragma unroll
        for (int nj = 0; nj < 4; ++nj) {
            const int p = pst[nj];
            if (p < NPIX) {
                ob[(size_t)(m + 0) * NPIX + p] = acc[mi][nj][0] + bv.x;
                ob[(size_t)(m + 1) * NPIX + p] = acc[mi][nj][1] + bv.y;
                ob[(size_t)(m + 2) * NPIX + p] = acc[mi][nj][2] + bv.z;
                ob[(size_t)(m + 3) * NPIX + p] = acc[mi][nj][3] + bv.w;
            }
        }
    }
}

extern "C" void kernel_launch(void* const* d_in, const int* in_sizes, int n_in,
                              void* d_out, int out_size, void* d_ws, size_t ws_size,
                              hipStream_t stream) {
    const float* x      = (const float*)d_in[0];
    const float* se     = (const float*)d_in[1];
    const float* weight = (const float*)d_in[2];
    const float* bias   = (const float*)d_in[3];
    float* out          = (float*)d_out;

    ushort* wgen2 = (ushort*)d_ws;
    ushort* xpad  = (ushort*)d_ws + XPAD_OFF;
    (void)ws_size; (void)in_sizes; (void)n_in; (void)out_size;

    prep<<<dim3(PREP_GRID), dim3(256), 0, stream>>>(weight, se, x, wgen2, xpad);
    dconv_mfma<<<dim3(BB * 4 * NT), dim3(256), 0, stream>>>(wgen2, xpad, bias, out);
}

// Round 15
// 146.128 us; speedup vs baseline: 1.2168x; 1.0024x over previous
//
#include <hip/hip_runtime.h>
#include <hip/hip_fp16.h>

#define BB    32
#define CIN   256
#define COUT  256
#define HH    28
#define WW    28
#define NPIX  784
#define HP    30
#define WP    30

#define BM    64
#define BN    128
#define NT    7               // 784 / 128 (ceil)

// workspace:
//   wgen2: fragment-ordered filters (16x16x32 MFMA), per (b,mtH) slice
//          294912 f16. Chunk (8 f16): (c32*9+khw)*512 + sub*64 + quad*16 + col
//          holds A[m = mtH*128 + sub*16 + col][ch = c32*32 + quad*8 .. +7]
//   xpad : [b][30][30][256] f16 zero-padded NHWC
#define SLICE_ELEMS 294912                       // 128 * 2304
#define WGEN_ELEMS  ((size_t)BB * 2 * SLICE_ELEMS)
#define XPAD_OFF    (WGEN_ELEMS)

#define PREP_GENW  512        // (og 0..31) x (c32 0..7) x (bh 0..1)
#define PREP_GENX  960
#define PREP_GRID  (PREP_GENW + PREP_GENX)

typedef _Float16 f16x8 __attribute__((ext_vector_type(8)));
typedef float    f32x4 __attribute__((ext_vector_type(4)));

static __device__ __forceinline__ ushort f2h_bits(float v) {
    __half h = __float2half(v);
    return *reinterpret_cast<ushort*>(&h);
}

static __device__ __forceinline__ void gll16(const ushort* g, ushort* l) {
    __builtin_amdgcn_global_load_lds(
        (const __attribute__((address_space(1))) unsigned int*)g,
        (__attribute__((address_space(3))) unsigned int*)l, 16, 0, 0);
}

#define KOFF(k) (((k) / 3) * 30 + ((k) % 3))

// ---------------------------------------------------------------------------
// Fused prep kernel (byte-identical to round 14).
// ---------------------------------------------------------------------------
__global__ __launch_bounds__(256) void prep(const float* __restrict__ weight,
                                            const float* __restrict__ se,
                                            const float* __restrict__ x,
                                            ushort* __restrict__ wgen2,
                                            ushort* __restrict__ xpad) {
    __shared__ __align__(16) char smem[29696];
    const int bid = blockIdx.x;
    const int tid = threadIdx.x;

    if (bid < PREP_GENW) {
        // ---- gen_w V5 ----
        const int og  = bid >> 4;
        const int bh  = (bid >> 3) & 1;
        const int c32 = bid & 7;
        const int ol  = tid >> 5;
        const int cl  = tid & 31;
        const int o   = og * 8 + ol;
        const int c   = c32 * 32 + cl;
        const int mtH = og >> 4;

        float*  se_sh = (float*)smem;                  // 1024 B
        ushort* w_lds = (ushort*)(smem + 1024);        // 2 x 2880 ushort

        se_sh[tid] = se[tid];

        float4 wr[18];
        const float4* wp = (const float4*)(weight + ((size_t)o * CIN + c) * 72);
#pragma unroll
        for (int i = 0; i < 18; ++i) wr[i] = wp[i];

        const int khw0 = tid >> 5;
        const int r0   = tid & 31;
        const int q0   = r0 >> 3;
        const int ol0  = r0 & 7;
        const int o0   = og * 8 + ol0;
        const int sub0 = (o0 >> 4) & 7, col0 = o0 & 15;
        const int dst0 = ((c32 * 9 + khw0) * 512 + sub0 * 64 + q0 * 16 + col0) * 8;
        const int src0 = (khw0 * 8 + ol0) * 40 + q0 * 8;
        const int q1   = tid >> 3;
        const int ol1  = tid & 7;
        const int o1   = og * 8 + ol1;
        const int sub1 = (o1 >> 4) & 7, col1 = o1 & 15;
        const int dst1 = ((c32 * 9 + 8) * 512 + sub1 * 64 + q1 * 16 + col1) * 8;
        const int src1 = (8 * 8 + ol1) * 40 + q1 * 8;

        __syncthreads();

        for (int bi = 0; bi < 16; ++bi) {
            const int b   = bh * 16 + bi;
            const int buf = (bi & 1) * 2880;
            const float s0 = se_sh[b * 8 + 0], s1 = se_sh[b * 8 + 1];
            const float s2 = se_sh[b * 8 + 2], s3 = se_sh[b * 8 + 3];
            const float s4 = se_sh[b * 8 + 4], s5 = se_sh[b * 8 + 5];
            const float s6 = se_sh[b * 8 + 6], s7 = se_sh[b * 8 + 7];
#pragma unroll
            for (int k = 0; k < 9; ++k) {
                const float4 w0 = wr[2 * k + 0];
                const float4 w1 = wr[2 * k + 1];
                const float v = w0.x * s0 + w0.y * s1 + w0.z * s2 + w0.w * s3
                              + w1.x * s4 + w1.y * s5 + w1.z * s6 + w1.w * s7;
                w_lds[buf + (k * 8 + ol) * 40 + cl] = f2h_bits(v);
            }
            __syncthreads();
            ushort* slice_base = wgen2 + (size_t)(b * 2 + mtH) * SLICE_ELEMS;
            *(uint4*)(slice_base + dst0) = *(const uint4*)(w_lds + buf + src0);
            if (tid < 32)
                *(uint4*)(slice_base + dst1) = *(const uint4*)(w_lds + buf + src1);
        }
    } else {
        // ---- gen_x ----
        const int idx = bid - PREP_GENW;
        const int hp  = idx % HP;
        const int b   = idx / HP;
        ushort* row = xpad + ((size_t)b * HP + hp) * WP * CIN;

        if (hp == 0 || hp == HP - 1) {
            uint* r32 = (uint*)row;
            for (int i = tid; i < (WP * CIN) / 2; i += 256) r32[i] = 0u;
            return;
        }
        {
            uint* c0 = (uint*)row;
            uint* c1 = (uint*)(row + (WP - 1) * CIN);
            if (tid < 128)       c0[tid] = 0u;
            else                 c1[tid - 128] = 0u;
        }
        float* lds = (float*)smem;
        const int h = hp - 1;
        const float* xr = x + (size_t)b * CIN * NPIX + h * WW;

        for (int f = tid; f < CIN * WW; f += 256) {
            const int cc = f / WW;
            const int w  = f % WW;
            lds[cc * (WW + 1) + w] = xr[(size_t)cc * NPIX + w];
        }
        __syncthreads();
        for (int g2 = tid; g2 < WW * CIN; g2 += 256) {
            const int w  = g2 >> 8;
            const int cc = g2 & 255;
            row[(w + 1) * CIN + cc] = f2h_bits(lds[cc * (WW + 1) + w]);
        }
    }
}

// ---------------------------------------------------------------------------
// dconv tile body, templated on NFR (n-fragments per wave).
// NFR=4: full 128-pixel N-tile. NFR=1: slim tail tile (nt=6, 16 valid pixels).
// A direct global->VGPR ring (3 slots, distance 2); bf ring (3 slots,
// distance 2); Psh dbuf, 1 barrier per c32.
// ---------------------------------------------------------------------------
template<int NFR>
static __device__ __forceinline__ void conv_tile(
    const ushort* __restrict__ wgen2, const ushort* __restrict__ xpad,
    const float* __restrict__ bias, float* __restrict__ out,
    ushort (*Psh)[7680], int b, int mtH, int mtl, int nt, int tid)
{
    const int lane = tid & 63;
    const int wave = tid >> 6;
    const int wm   = wave >> 1;
    const int wn   = wave & 1;
    const int col  = lane & 15;
    const int quad = lane >> 4;

    const int mo   = mtH * 128 + mtl * 64 + wm * 32;
    const int no   = nt * BN + wn * 64;
    const int h_lo = (nt * BN) / WW;

    const f16x8* ag = (const f16x8*)(wgen2 + (size_t)(b * 2 + mtH) * SLICE_ELEMS)
                      + (mtl * 4 + wm * 2) * 64 + lane;
    const ushort* xp = xpad + (size_t)b * HP * WP * CIN;

    int p_goff[4], p_loff[4];
    bool p_ok[4];
#pragma unroll
    for (int r = 0; r < 4; ++r) {
        const int j = r * 256 + tid;
        p_ok[r] = (j < 960);
        const int jj  = p_ok[r] ? j : 0;
        const int qc  = jj / 240;
        const int rem = jj % 240;
        const int rr  = rem / 30;
        const int ww  = rem % 30;
        int srow = h_lo + rr;
        if (srow > 29) srow = 29;
        p_goff[r] = (srow * WP + ww) * CIN + qc * 8;
        p_loff[r] = jj * 8;
    }

    int pixbase[NFR], pst[NFR];
#pragma unroll
    for (int j = 0; j < NFR; ++j) {
        const int p  = no + j * 16 + col;
        pst[j] = p;
        const int pc = p > (NPIX - 1) ? (NPIX - 1) : p;
        pixbase[j] = (pc / WW - h_lo) * 30 + (pc % WW);
    }

    f32x4 acc[2][NFR];
#pragma unroll
    for (int mi = 0; mi < 2; ++mi)
#pragma unroll
        for (int nj = 0; nj < NFR; ++nj)
            acc[mi][nj] = (f32x4){0.f, 0.f, 0.f, 0.f};

    // ---- prologue ----
#pragma unroll
    for (int r = 0; r < 4; ++r)
        if (p_ok[r]) gll16(xp + p_goff[r], &Psh[0][p_loff[r]]);

    f16x8 afr[3][2];
#pragma unroll
    for (int mi = 0; mi < 2; ++mi) afr[0][mi] = ag[mi * 64];
    {
        const f16x8* a1 = ag + (1 << 9);
#pragma unroll
        for (int mi = 0; mi < 2; ++mi) afr[1][mi] = a1[mi * 64];
    }

    f16x8 bfr[3][NFR];

    for (int c32 = 0; c32 < 8; ++c32) {
        __syncthreads();   // patch(c32) resident; prev buffer free

        if (c32 < 7) {
            const int nb = (c32 + 1) & 1;
#pragma unroll
            for (int r = 0; r < 4; ++r)
                if (p_ok[r]) gll16(xp + p_goff[r] + (c32 + 1) * 32,
                                   &Psh[nb][p_loff[r]]);
        }

        const f16x8* Pc = (const f16x8*)Psh[c32 & 1];

        // bf ring prologue: slots 0,1 = khw 0,1
#pragma unroll
        for (int j = 0; j < NFR; ++j) {
            bfr[0][j] = Pc[quad * 240 + pixbase[j] + KOFF(0)];
            bfr[1][j] = Pc[quad * 240 + pixbase[j] + KOFF(1)];
        }

#pragma unroll
        for (int khw = 0; khw < 9; ++khw) {
            const int st = c32 * 9 + khw;
            // A prefetch, distance 2 (slot khw%3; 9%3==0 keeps ring seamless)
            int sp = st + 2; if (sp > 71) sp = 71;
            const f16x8* apf = ag + ((size_t)sp << 9);
#pragma unroll
            for (int mi = 0; mi < 2; ++mi)
                afr[(khw + 2) % 3][mi] = apf[mi * 64];
            // bf prefetch, distance 2 (within c32)
            if (khw < 7) {
#pragma unroll
                for (int j = 0; j < NFR; ++j)
                    bfr[(khw + 2) % 3][j] =
                        Pc[quad * 240 + pixbase[j] + KOFF(khw + 2)];
            }
            // consume
#pragma unroll
            for (int mi = 0; mi < 2; ++mi)
#pragma unroll
                for (int nj = 0; nj < NFR; ++nj)
                    acc[mi][nj] = __builtin_amdgcn_mfma_f32_16x16x32_f16(
                        afr[khw % 3][mi], bfr[khw % 3][nj], acc[mi][nj], 0, 0, 0);
        }
    }

    // ---- epilogue ----
    float* ob = out + (size_t)b * COUT * NPIX;
#pragma unroll
    for (int mi = 0; mi < 2; ++mi) {
        const int m = mo + mi * 16 + quad * 4;
        const float4 bv = *(const float4*)(bias + m);
#pragma unroll
        for (int nj = 0; nj < NFR; ++nj) {
            const int p = pst[nj];
            if (p < NPIX) {
                ob[(size_t)(m + 0) * NPIX + p] = acc[mi][nj][0] + bv.x;
                ob[(size_t)(m + 1) * NPIX + p] = acc[mi][nj][1] + bv.y;
                ob[(size_t)(m + 2) * NPIX + p] = acc[mi][nj][2] + bv.z;
                ob[(size_t)(m + 3) * NPIX + p] = acc[mi][nj][3] + bv.w;
            }
        }
    }
}

// ---------------------------------------------------------------------------
// dconv: r14 structure + slim tail (nt==6 runs NFR=1: pixels 768-783 only;
// 10.7% of block-work eliminated) + bf ring distance 2. Grid 896, XCD-grouped.
// ---------------------------------------------------------------------------
__global__ __launch_bounds__(256, 4) void dconv_mfma(const ushort* __restrict__ wgen2,
                                                     const ushort* __restrict__ xpad,
                                                     const float* __restrict__ bias,
                                                     float* __restrict__ out) {
    const int bid    = blockIdx.x;
    const int g      = bid & 7;
    const int s      = bid >> 3;           // 0..111
    const int t      = s % 14;
    const int nt     = t % 7;
    const int mtl    = t / 7;
    const int slice2 = g + 8 * (s / 14);   // 0..63 = b*2 + mtH
    const int b      = slice2 >> 1;
    const int mtH    = slice2 & 1;
    const int tid    = threadIdx.x;

    __shared__ ushort Psh[2][7680];        // 2 x 15360 B

    if (nt == 6)
        conv_tile<1>(wgen2, xpad, bias, out, Psh, b, mtH, mtl, nt, tid);
    else
        conv_tile<4>(wgen2, xpad, bias, out, Psh, b, mtH, mtl, nt, tid);
}

extern "C" void kernel_launch(void* const* d_in, const int* in_sizes, int n_in,
                              void* d_out, int out_size, void* d_ws, size_t ws_size,
                              hipStream_t stream) {
    const float* x      = (const float*)d_in[0];
    const float* se     = (const float*)d_in[1];
    const float* weight = (const float*)d_in[2];
    const float* bias   = (const float*)d_in[3];
    float* out          = (float*)d_out;

    ushort* wgen2 = (ushort*)d_ws;
    ushort* xpad  = (ushort*)d_ws + XPAD_OFF;
    (void)ws_size; (void)in_sizes; (void)n_in; (void)out_size;

    prep<<<dim3(PREP_GRID), dim3(256), 0, stream>>>(weight, se, x, wgen2, xpad);
    dconv_mfma<<<dim3(BB * 4 * NT), dim3(256), 0, stream>>>(wgen2, xpad, bias, out);
}